// Round 1
// baseline (1861.443 us; speedup 1.0000x reference)
//
#include <hip/hip_runtime.h>
#include <hip/hip_bf16.h>
#include <math.h>

namespace {
constexpr int kDModel = 2048;
constexpr int kHeads  = 32;
constexpr int kState  = 64;
constexpr int kP      = 64;    // head dim = D_MODEL / N_HEADS
constexpr int kChunk  = 256;
constexpr int kNChunk = 16;    // SEQLEN / CHUNK
constexpr int kBatch  = 2;
constexpr int kSeq    = 4096;
constexpr int kM      = kBatch * kSeq;  // 8192 rows
}

__device__ __forceinline__ void load4(const float* __restrict__ p, float d[4]) {
    const float4 v = *reinterpret_cast<const float4*>(p);
    d[0] = v.x; d[1] = v.y; d[2] = v.z; d[3] = v.w;
}
__device__ __forceinline__ void load4(const __hip_bfloat16* __restrict__ p, float d[4]) {
    const ushort4 v = *reinterpret_cast<const ushort4*>(p);
    d[0] = __uint_as_float((unsigned)v.x << 16);
    d[1] = __uint_as_float((unsigned)v.y << 16);
    d[2] = __uint_as_float((unsigned)v.z << 16);
    d[3] = __uint_as_float((unsigned)v.w << 16);
}

// C[M,N] = A[M,K] @ W[N,K]^T + bias, ACT==1 -> softplus. BM=128,BN=64,BK=16,
// 256 threads, 8x4 micro-tile, transposed LDS so fragment reads are contiguous.
template <int ACT, typename AT>
__global__ __launch_bounds__(256)
void gemm_bt(const AT* __restrict__ A, const float* __restrict__ W,
             const float* __restrict__ bias, float* __restrict__ Cout,
             int N, int K)
{
    constexpr int BK = 16;
    __shared__ float Ast[BK][128];
    __shared__ float Wst[BK][64];
    const int tid = threadIdx.x;
    const int tx = tid & 15, ty = tid >> 4;
    const int m0 = blockIdx.y * 128;
    const int n0 = blockIdx.x * 64;
    const int lr = tid >> 2;          // 0..63
    const int lc = (tid & 3) << 2;    // 0,4,8,12
    float acc[8][4] = {};
    for (int k0 = 0; k0 < K; k0 += BK) {
        float t0[4], t1[4], tw[4];
        load4(A + (size_t)(m0 + lr) * K + (k0 + lc), t0);
        load4(A + (size_t)(m0 + lr + 64) * K + (k0 + lc), t1);
        if (n0 + lr < N) load4(W + (size_t)(n0 + lr) * K + (k0 + lc), tw);
        else { tw[0] = 0.f; tw[1] = 0.f; tw[2] = 0.f; tw[3] = 0.f; }
        __syncthreads();   // previous iter's LDS reads complete
        #pragma unroll
        for (int q = 0; q < 4; ++q) {
            Ast[lc + q][lr]      = t0[q];
            Ast[lc + q][lr + 64] = t1[q];
            Wst[lc + q][lr]      = tw[q];
        }
        __syncthreads();
        #pragma unroll
        for (int k = 0; k < BK; ++k) {
            float av[8], wv[4];
            #pragma unroll
            for (int i = 0; i < 8; ++i) av[i] = Ast[k][ty * 8 + i];
            #pragma unroll
            for (int j = 0; j < 4; ++j) wv[j] = Wst[k][tx * 4 + j];
            #pragma unroll
            for (int i = 0; i < 8; ++i)
                #pragma unroll
                for (int j = 0; j < 4; ++j)
                    acc[i][j] = fmaf(av[i], wv[j], acc[i][j]);
        }
    }
    const int nb = n0 + tx * 4;
    if (nb + 3 < N) {
        #pragma unroll
        for (int i = 0; i < 8; ++i) {
            const int m = m0 + ty * 8 + i;
            float4 v;
            v.x = acc[i][0] + bias[nb + 0];
            v.y = acc[i][1] + bias[nb + 1];
            v.z = acc[i][2] + bias[nb + 2];
            v.w = acc[i][3] + bias[nb + 3];
            if (ACT == 1) {
                v.x = (v.x > 20.f) ? v.x : log1pf(expf(v.x));
                v.y = (v.y > 20.f) ? v.y : log1pf(expf(v.y));
                v.z = (v.z > 20.f) ? v.z : log1pf(expf(v.z));
                v.w = (v.w > 20.f) ? v.w : log1pf(expf(v.w));
            }
            *reinterpret_cast<float4*>(Cout + (size_t)m * N + nb) = v;
        }
    }
}

// Per (b,h,chunk): Acs[l] = inclusive cumsum_l( dt[l] * A[h] ), A = -exp(A_log)
__global__ __launch_bounds__(kChunk)
void dtcumsum_kernel(const float* __restrict__ dtm, const float* __restrict__ A_log,
                     float* __restrict__ Acs)
{
    const int blk = blockIdx.x;                  // (bi*kHeads+hi)*kNChunk + ci
    const int ci = blk & (kNChunk - 1);
    const int hi = (blk >> 4) & (kHeads - 1);
    const int bi = blk >> 9;
    const int t = threadIdx.x;
    const float Ah = -expf(A_log[hi]);
    __shared__ float s[kChunk];
    s[t] = dtm[((size_t)bi * kSeq + ci * kChunk + t) * kHeads + hi] * Ah;
    __syncthreads();
    for (int off = 1; off < kChunk; off <<= 1) {
        const float add = (t >= off) ? s[t - off] : 0.f;
        __syncthreads();
        s[t] += add;
        __syncthreads();
    }
    Acs[((size_t)(bi * kHeads + hi) * kNChunk + ci) * kChunk + t] = s[t];
}

// states[b,c,h,p,n] = sum_l B[b,t,n] * exp(Acs[last]-Acs[l]) * x[b,t,h*64+p]*dt[b,t,h]
__global__ __launch_bounds__(256)
void states_kernel(const float* __restrict__ x, const float* __restrict__ dtm,
                   const float* __restrict__ Bmat, const float* __restrict__ Acs,
                   float* __restrict__ states)
{
    const int blk = blockIdx.x;                  // (bi*kNChunk+ci)*kHeads + hi
    const int hi = blk & (kHeads - 1);
    const int ci = (blk >> 5) & (kNChunk - 1);
    const int bi = blk >> 9;
    const float* acs = Acs + ((size_t)(bi * kHeads + hi) * kNChunk + ci) * kChunk;
    const float a_last = acs[kChunk - 1];
    __shared__ float Bs[32][kState];
    __shared__ float Xs[32][kP];
    const int tid = threadIdx.x;
    const int tx = tid & 15, ty = tid >> 4;
    float acc[4][4] = {};
    for (int l0 = 0; l0 < kChunk; l0 += 32) {
        #pragma unroll
        for (int e = 0; e < 8; ++e) {
            const int idx = e * 256 + tid;
            const int r = idx >> 6, cc = idx & 63;
            const size_t tg = (size_t)bi * kSeq + ci * kChunk + l0 + r;
            Bs[r][cc] = Bmat[tg * kState + cc];
            const float decay = expf(a_last - acs[l0 + r]);
            const float dtv = dtm[tg * kHeads + hi];
            Xs[r][cc] = x[tg * kDModel + hi * kP + cc] * dtv * decay;
        }
        __syncthreads();
        #pragma unroll
        for (int l = 0; l < 32; ++l) {
            float xv[4], bv[4];
            #pragma unroll
            for (int i = 0; i < 4; ++i) xv[i] = Xs[l][ty + 16 * i];
            #pragma unroll
            for (int j = 0; j < 4; ++j) bv[j] = Bs[l][tx + 16 * j];
            #pragma unroll
            for (int i = 0; i < 4; ++i)
                #pragma unroll
                for (int j = 0; j < 4; ++j)
                    acc[i][j] = fmaf(xv[i], bv[j], acc[i][j]);
        }
        __syncthreads();
    }
    float* sp = states + ((size_t)(bi * kNChunk + ci) * kHeads + hi) * (kP * kState);
    #pragma unroll
    for (int i = 0; i < 4; ++i)
        #pragma unroll
        for (int j = 0; j < 4; ++j)
            sp[(size_t)(ty + 16 * i) * kState + (tx + 16 * j)] = acc[i][j];
}

// prevs[b,0,h]=0 ; prevs[b,c,h] = exp(a[c-1])*prevs[b,c-1,h] + states[b,c-1,h]
__global__ __launch_bounds__(256)
void chunkscan_kernel(const float* __restrict__ states, const float* __restrict__ Acs,
                      float* __restrict__ prevs)
{
    const int hi = blockIdx.x & (kHeads - 1);
    const int bi = blockIdx.x >> 5;
    const int tid = threadIdx.x;
    __shared__ float ea[kNChunk];
    if (tid < kNChunk)
        ea[tid] = expf(Acs[((size_t)(bi * kHeads + hi) * kNChunk + tid) * kChunk + kChunk - 1]);
    __syncthreads();
    float P[16];
    {
        float* pp = prevs + ((size_t)(bi * kNChunk + 0) * kHeads + hi) * (kP * kState);
        #pragma unroll
        for (int e = 0; e < 16; ++e) { P[e] = 0.f; pp[e * 256 + tid] = 0.f; }
    }
    for (int c = 1; c < kNChunk; ++c) {
        const float* sp = states + ((size_t)(bi * kNChunk + (c - 1)) * kHeads + hi) * (kP * kState);
        float* pp = prevs + ((size_t)(bi * kNChunk + c) * kHeads + hi) * (kP * kState);
        const float e_ = ea[c - 1];
        #pragma unroll
        for (int e = 0; e < 16; ++e) {
            P[e] = fmaf(e_, P[e], sp[e * 256 + tid]);
            pp[e * 256 + tid] = P[e];
        }
    }
}

// Per (b,c,h): Y[l,p] = sum_{s<=l,n} C[l,n]B[s,n]exp(Acs[l]-Acs[s]) x[s]dt[s]
//                      + exp(Acs[l]) * sum_n C[l,n] P[p,n]  +  D[h]*x[l,p]
// Flash-style 64x64 tiles; BX buffer is time-shared between P / B / Xdt.
__global__ __launch_bounds__(256)
void ychunk_kernel(const float* __restrict__ x, const float* __restrict__ dtm,
                   const float* __restrict__ Bmat, const float* __restrict__ Cmat,
                   const float* __restrict__ Acs, const float* __restrict__ prevs,
                   const float* __restrict__ Dvec, __hip_bfloat16* __restrict__ Y)
{
    const int blk = blockIdx.x;                  // (bi*kNChunk+ci)*kHeads + hi
    const int hi = blk & (kHeads - 1);
    const int ci = (blk >> 5) & (kNChunk - 1);
    const int bi = blk >> 9;
    __shared__ float acs_s[kChunk];
    __shared__ float Cs[64][kState + 1];
    __shared__ float BX[64][kState + 1];
    __shared__ float Ss[64][65];
    const int tid = threadIdx.x;
    const int tx = tid & 15, ty = tid >> 4;
    acs_s[tid] = Acs[((size_t)(bi * kHeads + hi) * kNChunk + ci) * kChunk + tid];
    const float Dh = Dvec[hi];
    const size_t rowbase = (size_t)bi * kSeq + ci * kChunk;
    const float* pp = prevs + ((size_t)(bi * kNChunk + ci) * kHeads + hi) * (kP * kState);

    for (int lt = 0; lt < 4; ++lt) {
        // stage C l-tile and P (into BX)
        #pragma unroll
        for (int e = 0; e < 16; ++e) {
            const int idx = e * 256 + tid;
            const int r = idx >> 6, cc = idx & 63;
            const size_t tg = rowbase + lt * 64 + r;
            Cs[r][cc] = Cmat[tg * kState + cc];
            BX[r][cc] = pp[idx];  // P[p=r][n=cc]
        }
        __syncthreads();
        float yacc[4][4];
        {   // Y_off = exp(Acs[l]) * (C @ P^T)
            float oacc[4][4] = {};
            for (int n = 0; n < kState; ++n) {
                float cv[4], pv[4];
                #pragma unroll
                for (int i = 0; i < 4; ++i) cv[i] = Cs[ty + 16 * i][n];
                #pragma unroll
                for (int j = 0; j < 4; ++j) pv[j] = BX[tx + 16 * j][n];
                #pragma unroll
                for (int i = 0; i < 4; ++i)
                    #pragma unroll
                    for (int j = 0; j < 4; ++j)
                        oacc[i][j] = fmaf(cv[i], pv[j], oacc[i][j]);
            }
            #pragma unroll
            for (int i = 0; i < 4; ++i) {
                const float sds = expf(acs_s[lt * 64 + ty + 16 * i]);
                #pragma unroll
                for (int j = 0; j < 4; ++j) yacc[i][j] = sds * oacc[i][j];
            }
        }
        __syncthreads();   // P reads done before BX reuse
        for (int st = 0; st <= lt; ++st) {
            // stage B s-tile into BX
            #pragma unroll
            for (int e = 0; e < 16; ++e) {
                const int idx = e * 256 + tid;
                const int r = idx >> 6, cc = idx & 63;
                const size_t tg = rowbase + st * 64 + r;
                BX[r][cc] = Bmat[tg * kState + cc];
            }
            __syncthreads();
            float sacc[4][4] = {};
            for (int n = 0; n < kState; ++n) {
                float cv[4], bv[4];
                #pragma unroll
                for (int i = 0; i < 4; ++i) cv[i] = Cs[ty + 16 * i][n];
                #pragma unroll
                for (int j = 0; j < 4; ++j) bv[j] = BX[tx + 16 * j][n];
                #pragma unroll
                for (int i = 0; i < 4; ++i)
                    #pragma unroll
                    for (int j = 0; j < 4; ++j)
                        sacc[i][j] = fmaf(cv[i], bv[j], sacc[i][j]);
            }
            __syncthreads();   // B reads done before BX reuse for Xdt
            #pragma unroll
            for (int i = 0; i < 4; ++i) {
                const int li = lt * 64 + ty + 16 * i;
                #pragma unroll
                for (int j = 0; j < 4; ++j) {
                    const int sj = st * 64 + tx + 16 * j;
                    Ss[ty + 16 * i][tx + 16 * j] =
                        (sj <= li) ? sacc[i][j] * expf(acs_s[li] - acs_s[sj]) : 0.f;
                }
            }
            #pragma unroll
            for (int e = 0; e < 16; ++e) {
                const int idx = e * 256 + tid;
                const int r = idx >> 6, cc = idx & 63;
                const size_t tg = rowbase + st * 64 + r;
                BX[r][cc] = x[tg * kDModel + hi * kP + cc] * dtm[tg * kHeads + hi];
            }
            __syncthreads();
            for (int s = 0; s < 64; ++s) {
                float sv[4], xv[4];
                #pragma unroll
                for (int i = 0; i < 4; ++i) sv[i] = Ss[ty + 16 * i][s];
                #pragma unroll
                for (int j = 0; j < 4; ++j) xv[j] = BX[s][tx + 16 * j];
                #pragma unroll
                for (int i = 0; i < 4; ++i)
                    #pragma unroll
                    for (int j = 0; j < 4; ++j)
                        yacc[i][j] = fmaf(sv[i], xv[j], yacc[i][j]);
            }
            __syncthreads();   // Ss + Xdt reads done
        }
        // epilogue: += D*x, store bf16 Y
        #pragma unroll
        for (int i = 0; i < 4; ++i) {
            const int li = lt * 64 + ty + 16 * i;
            const size_t tg = rowbase + li;
            #pragma unroll
            for (int j = 0; j < 4; ++j) {
                const int pj = tx + 16 * j;
                const float v = yacc[i][j] + Dh * x[tg * kDModel + hi * kP + pj];
                Y[tg * kDModel + hi * kP + pj] = __float2bfloat16(v);
            }
        }
    }
}

extern "C" void kernel_launch(void* const* d_in, const int* in_sizes, int n_in,
                              void* d_out, int out_size, void* d_ws, size_t ws_size,
                              hipStream_t stream)
{
    (void)in_sizes; (void)n_in; (void)out_size; (void)ws_size;
    const float* x     = (const float*)d_in[0];
    const float* A_log = (const float*)d_in[1];
    const float* Dvec  = (const float*)d_in[2];
    const float* B_w   = (const float*)d_in[3];
    const float* B_b   = (const float*)d_in[4];
    const float* C_w   = (const float*)d_in[5];
    const float* C_b   = (const float*)d_in[6];
    const float* dt_w  = (const float*)d_in[7];
    const float* dt_b  = (const float*)d_in[8];
    const float* out_w = (const float*)d_in[9];
    const float* out_b = (const float*)d_in[10];
    float* out = (float*)d_out;

    // workspace layout (fp32 except Y)
    float* ws = (float*)d_ws;
    float* Bmat   = ws;                                                  // 2*4096*64
    float* Cmat   = Bmat + (size_t)kBatch * kSeq * kState;
    float* dtm    = Cmat + (size_t)kBatch * kSeq * kState;               // 2*4096*32
    float* Acs    = dtm + (size_t)kBatch * kSeq * kHeads;                // 2*32*16*256
    float* states = Acs + (size_t)kBatch * kHeads * kNChunk * kChunk;    // 2*16*32*64*64
    float* prevs  = states + (size_t)kBatch * kNChunk * kHeads * kP * kState;
    __hip_bfloat16* Y = (__hip_bfloat16*)(prevs + (size_t)kBatch * kNChunk * kHeads * kP * kState);

    const dim3 blk(256);
    // projections: B, C, dt(softplus)
    gemm_bt<0, float><<<dim3(1, kM / 128), blk, 0, stream>>>(x, B_w, B_b, Bmat, kState, kDModel);
    gemm_bt<0, float><<<dim3(1, kM / 128), blk, 0, stream>>>(x, C_w, C_b, Cmat, kState, kDModel);
    gemm_bt<1, float><<<dim3(1, kM / 128), blk, 0, stream>>>(x, dt_w, dt_b, dtm, kHeads, kDModel);
    // per-chunk cumulative decay
    dtcumsum_kernel<<<dim3(kBatch * kHeads * kNChunk), dim3(kChunk), 0, stream>>>(dtm, A_log, Acs);
    // per-chunk end states
    states_kernel<<<dim3(kBatch * kNChunk * kHeads), blk, 0, stream>>>(x, dtm, Bmat, Acs, states);
    // inter-chunk recurrence (16 steps)
    chunkscan_kernel<<<dim3(kBatch * kHeads), blk, 0, stream>>>(states, Acs, prevs);
    // intra-chunk Y (diag + off + D*x), bf16 staging
    ychunk_kernel<<<dim3(kBatch * kNChunk * kHeads), blk, 0, stream>>>(x, dtm, Bmat, Cmat, Acs, prevs, Dvec, Y);
    // out-projection
    gemm_bt<0, __hip_bfloat16><<<dim3(kDModel / 64, kM / 128), blk, 0, stream>>>(Y, out_w, out_b, out, kDModel, kDModel);
}

// Round 2
// 687.615 us; speedup vs baseline: 2.7071x; 2.7071x over previous
//
#include <hip/hip_runtime.h>
#include <hip/hip_bf16.h>
#include <math.h>

namespace {
constexpr int kDModel = 2048;
constexpr int kHeads  = 32;
constexpr int kState  = 64;
constexpr int kP      = 64;    // head dim = D_MODEL / N_HEADS
constexpr int kChunk  = 256;
constexpr int kNChunk = 16;    // SEQLEN / CHUNK
constexpr int kBatch  = 2;
constexpr int kSeq    = 4096;
constexpr int kM      = kBatch * kSeq;  // 8192 rows
}

typedef __bf16 bf16_t;
typedef __attribute__((ext_vector_type(8))) __bf16 bf16x8;
typedef __attribute__((ext_vector_type(4))) float f32x4;

__device__ __forceinline__ void gload_lds16(const void* g, void* l) {
    __builtin_amdgcn_global_load_lds(
        (const __attribute__((address_space(1))) void*)g,
        (__attribute__((address_space(3))) void*)l,
        16, 0, 0);
}

// ---------------------------------------------------------------------------
// MFMA bf16 GEMM: C[M,N] = A[M,K] @ W[N,K]^T (+bias). 128x128 tile, BK=32,
// 256 threads = 4 waves in 2x2, each wave 64x64 via 4x4 of 16x16x32 MFMAs.
// m97-verified structure: global_load_lds width=16, single-buffered LDS.
// MODE 0: plain, store o0[M x N] + b0.  MODE 1: BCdt split epilogue.
// ---------------------------------------------------------------------------
template <int MODE>
__global__ __launch_bounds__(256)
void gemm_mfma(const bf16_t* __restrict__ A, const bf16_t* __restrict__ W,
               int K, int N,
               const float* __restrict__ b0, const float* __restrict__ b1,
               const float* __restrict__ b2,
               float* __restrict__ o0, float* __restrict__ o1,
               float* __restrict__ o2)
{
    __shared__ short AstS[128 * 32];
    __shared__ short WstS[128 * 32];
    const int tid  = threadIdx.x;
    const int lane = tid & 63;
    const int wave = tid >> 6;
    const int wm = (wave >> 1) * 64;
    const int wn = (wave & 1) * 64;
    const int l15 = lane & 15, quad = lane >> 4;
    const int m0 = blockIdx.y * 128;
    const int n0 = blockIdx.x * 128;
    const int u0 = tid, u1 = tid + 256;   // 16B staging units

    f32x4 acc[4][4];
    #pragma unroll
    for (int i = 0; i < 4; ++i)
        #pragma unroll
        for (int j = 0; j < 4; ++j)
            acc[i][j] = (f32x4){0.f, 0.f, 0.f, 0.f};

    for (int k0 = 0; k0 < K; k0 += 32) {
        gload_lds16(A + (size_t)(m0 + (u0 >> 2)) * K + k0 + (u0 & 3) * 8, AstS + u0 * 8);
        gload_lds16(A + (size_t)(m0 + (u1 >> 2)) * K + k0 + (u1 & 3) * 8, AstS + u1 * 8);
        gload_lds16(W + (size_t)(n0 + (u0 >> 2)) * K + k0 + (u0 & 3) * 8, WstS + u0 * 8);
        gload_lds16(W + (size_t)(n0 + (u1 >> 2)) * K + k0 + (u1 & 3) * 8, WstS + u1 * 8);
        __syncthreads();   // drains vmcnt (global_load_lds) before LDS reads
        bf16x8 af[4], bfr[4];
        #pragma unroll
        for (int mi = 0; mi < 4; ++mi)
            af[mi] = *reinterpret_cast<const bf16x8*>(&AstS[(wm + mi * 16 + l15) * 32 + quad * 8]);
        #pragma unroll
        for (int ni = 0; ni < 4; ++ni)
            bfr[ni] = *reinterpret_cast<const bf16x8*>(&WstS[(wn + ni * 16 + l15) * 32 + quad * 8]);
        #pragma unroll
        for (int mi = 0; mi < 4; ++mi)
            #pragma unroll
            for (int ni = 0; ni < 4; ++ni)
                acc[mi][ni] = __builtin_amdgcn_mfma_f32_16x16x32_bf16(
                    af[mi], bfr[ni], acc[mi][ni], 0, 0, 0);
        __syncthreads();   // LDS reads done before next stage overwrites
    }

    // C/D layout: col = lane&15, row = quad*4 + reg  [m89-verified]
    #pragma unroll
    for (int mi = 0; mi < 4; ++mi) {
        #pragma unroll
        for (int reg = 0; reg < 4; ++reg) {
            const int r = m0 + wm + mi * 16 + quad * 4 + reg;
            #pragma unroll
            for (int ni = 0; ni < 4; ++ni) {
                const float v = acc[mi][ni][reg];
                if (MODE == 0) {
                    const int c = n0 + wn + ni * 16 + l15;
                    o0[(size_t)r * N + c] = v + b0[c];
                } else {
                    const int n = n0 + wn + ni * 16 + l15;
                    if (n < 64) {
                        o0[(size_t)r * 64 + n] = v + b0[n];
                    } else if (n < 128) {
                        o1[(size_t)r * 64 + (n - 64)] = v + b1[n - 64];
                    } else if (n < 160) {
                        float z = v + b2[n - 128];
                        o2[(size_t)r * 32 + (n - 128)] = (z > 20.f) ? z : log1pf(expf(z));
                    }
                }
            }
        }
    }
}

// float -> bf16 convert, 4 elems/thread (n divisible by 4*256)
__global__ __launch_bounds__(256)
void cvt_bf16_kernel(const float* __restrict__ src, bf16_t* __restrict__ dst, int n)
{
    const int i = (blockIdx.x * 256 + threadIdx.x) * 4;
    if (i + 3 < n) {
        const float4 v = *reinterpret_cast<const float4*>(src + i);
        dst[i + 0] = (bf16_t)__float2bfloat16(v.x);
        dst[i + 1] = (bf16_t)__float2bfloat16(v.y);
        dst[i + 2] = (bf16_t)__float2bfloat16(v.z);
        dst[i + 3] = (bf16_t)__float2bfloat16(v.w);
    }
}

// Concat [B_w;C_w;dt_w] into bf16 [256,2048], rows 160..255 zero
__global__ __launch_bounds__(256)
void pack_w_kernel(const float* __restrict__ B_w, const float* __restrict__ C_w,
                   const float* __restrict__ dt_w, bf16_t* __restrict__ wcat)
{
    const int idx = blockIdx.x * 256 + threadIdx.x;   // 256*2048 total
    const int r = idx >> 11, k = idx & 2047;
    float v = 0.f;
    if (r < 64)       v = B_w[r * 2048 + k];
    else if (r < 128) v = C_w[(r - 64) * 2048 + k];
    else if (r < 160) v = dt_w[(r - 128) * 2048 + k];
    wcat[idx] = (bf16_t)__float2bfloat16(v);
}

// Per (b,h,chunk): Acs[l] = inclusive cumsum_l( dt[l] * A[h] ), A = -exp(A_log)
__global__ __launch_bounds__(kChunk)
void dtcumsum_kernel(const float* __restrict__ dtm, const float* __restrict__ A_log,
                     float* __restrict__ Acs)
{
    const int blk = blockIdx.x;                  // (bi*kHeads+hi)*kNChunk + ci
    const int ci = blk & (kNChunk - 1);
    const int hi = (blk >> 4) & (kHeads - 1);
    const int bi = blk >> 9;
    const int t = threadIdx.x;
    const float Ah = -expf(A_log[hi]);
    __shared__ float s[kChunk];
    s[t] = dtm[((size_t)bi * kSeq + ci * kChunk + t) * kHeads + hi] * Ah;
    __syncthreads();
    for (int off = 1; off < kChunk; off <<= 1) {
        const float add = (t >= off) ? s[t - off] : 0.f;
        __syncthreads();
        s[t] += add;
        __syncthreads();
    }
    Acs[((size_t)(bi * kHeads + hi) * kNChunk + ci) * kChunk + t] = s[t];
}

// states[b,c,h,p,n] = sum_l B[t,n] * exp(Acs[last]-Acs[l]) * x[t,h*64+p]*dt[t,h]
__global__ __launch_bounds__(256)
void states_kernel(const float* __restrict__ x, const float* __restrict__ dtm,
                   const float* __restrict__ Bmat, const float* __restrict__ Acs,
                   float* __restrict__ states)
{
    const int blk = blockIdx.x;                  // (bi*kNChunk+ci)*kHeads + hi
    const int hi = blk & (kHeads - 1);
    const int ci = (blk >> 5) & (kNChunk - 1);
    const int bi = blk >> 9;
    const float* acs = Acs + ((size_t)(bi * kHeads + hi) * kNChunk + ci) * kChunk;
    const float a_last = acs[kChunk - 1];
    __shared__ float Bs[32][kState];
    __shared__ float Xs[32][kP];
    const int tid = threadIdx.x;
    const int tx = tid & 15, ty = tid >> 4;
    float acc[4][4] = {};
    for (int l0 = 0; l0 < kChunk; l0 += 32) {
        #pragma unroll
        for (int e = 0; e < 8; ++e) {
            const int idx = e * 256 + tid;
            const int r = idx >> 6, cc = idx & 63;
            const size_t tg = (size_t)bi * kSeq + ci * kChunk + l0 + r;
            Bs[r][cc] = Bmat[tg * kState + cc];
            const float decay = expf(a_last - acs[l0 + r]);
            const float dtv = dtm[tg * kHeads + hi];
            Xs[r][cc] = x[tg * kDModel + hi * kP + cc] * dtv * decay;
        }
        __syncthreads();
        #pragma unroll
        for (int l = 0; l < 32; ++l) {
            float xv[4], bv[4];
            #pragma unroll
            for (int i = 0; i < 4; ++i) xv[i] = Xs[l][ty + 16 * i];
            #pragma unroll
            for (int j = 0; j < 4; ++j) bv[j] = Bs[l][tx + 16 * j];
            #pragma unroll
            for (int i = 0; i < 4; ++i)
                #pragma unroll
                for (int j = 0; j < 4; ++j)
                    acc[i][j] = fmaf(xv[i], bv[j], acc[i][j]);
        }
        __syncthreads();
    }
    float* sp = states + ((size_t)(bi * kNChunk + ci) * kHeads + hi) * (kP * kState);
    #pragma unroll
    for (int i = 0; i < 4; ++i)
        #pragma unroll
        for (int j = 0; j < 4; ++j)
            sp[(size_t)(ty + 16 * i) * kState + (tx + 16 * j)] = acc[i][j];
}

// prevs[b,0,h]=0 ; prevs[b,c,h] = exp(a[c-1])*prevs[b,c-1,h] + states[b,c-1,h]
__global__ __launch_bounds__(256)
void chunkscan_kernel(const float* __restrict__ states, const float* __restrict__ Acs,
                      float* __restrict__ prevs)
{
    const int hi = blockIdx.x & (kHeads - 1);
    const int bi = blockIdx.x >> 5;
    const int tid = threadIdx.x;
    __shared__ float ea[kNChunk];
    if (tid < kNChunk)
        ea[tid] = expf(Acs[((size_t)(bi * kHeads + hi) * kNChunk + tid) * kChunk + kChunk - 1]);
    __syncthreads();
    float P[16];
    {
        float* pp = prevs + ((size_t)(bi * kNChunk + 0) * kHeads + hi) * (kP * kState);
        #pragma unroll
        for (int e = 0; e < 16; ++e) { P[e] = 0.f; pp[e * 256 + tid] = 0.f; }
    }
    for (int c = 1; c < kNChunk; ++c) {
        const float* sp = states + ((size_t)(bi * kNChunk + (c - 1)) * kHeads + hi) * (kP * kState);
        float* pp = prevs + ((size_t)(bi * kNChunk + c) * kHeads + hi) * (kP * kState);
        const float e_ = ea[c - 1];
        #pragma unroll
        for (int e = 0; e < 16; ++e) {
            P[e] = fmaf(e_, P[e], sp[e * 256 + tid]);
            pp[e * 256 + tid] = P[e];
        }
    }
}

// Per (b,c,h): Y[l,p] = sum_{s<=l,n} C[l,n]B[s,n]exp(Acs[l]-Acs[s]) x[s]dt[s]
//                      + exp(Acs[l]) * sum_n C[l,n] P[p,n]  +  D[h]*x[l,p]
__global__ __launch_bounds__(256)
void ychunk_kernel(const float* __restrict__ x, const float* __restrict__ dtm,
                   const float* __restrict__ Bmat, const float* __restrict__ Cmat,
                   const float* __restrict__ Acs, const float* __restrict__ prevs,
                   const float* __restrict__ Dvec, bf16_t* __restrict__ Y)
{
    const int blk = blockIdx.x;                  // (bi*kNChunk+ci)*kHeads + hi
    const int hi = blk & (kHeads - 1);
    const int ci = (blk >> 5) & (kNChunk - 1);
    const int bi = blk >> 9;
    __shared__ float acs_s[kChunk];
    __shared__ float Cs[64][kState + 1];
    __shared__ float BX[64][kState + 1];
    __shared__ float Ss[64][65];
    const int tid = threadIdx.x;
    const int tx = tid & 15, ty = tid >> 4;
    acs_s[tid] = Acs[((size_t)(bi * kHeads + hi) * kNChunk + ci) * kChunk + tid];
    const float Dh = Dvec[hi];
    const size_t rowbase = (size_t)bi * kSeq + ci * kChunk;
    const float* pp = prevs + ((size_t)(bi * kNChunk + ci) * kHeads + hi) * (kP * kState);

    for (int lt = 0; lt < 4; ++lt) {
        #pragma unroll
        for (int e = 0; e < 16; ++e) {
            const int idx = e * 256 + tid;
            const int r = idx >> 6, cc = idx & 63;
            const size_t tg = rowbase + lt * 64 + r;
            Cs[r][cc] = Cmat[tg * kState + cc];
            BX[r][cc] = pp[idx];  // P[p=r][n=cc]
        }
        __syncthreads();
        float yacc[4][4];
        {   // Y_off = exp(Acs[l]) * (C @ P^T)
            float oacc[4][4] = {};
            for (int n = 0; n < kState; ++n) {
                float cv[4], pv[4];
                #pragma unroll
                for (int i = 0; i < 4; ++i) cv[i] = Cs[ty + 16 * i][n];
                #pragma unroll
                for (int j = 0; j < 4; ++j) pv[j] = BX[tx + 16 * j][n];
                #pragma unroll
                for (int i = 0; i < 4; ++i)
                    #pragma unroll
                    for (int j = 0; j < 4; ++j)
                        oacc[i][j] = fmaf(cv[i], pv[j], oacc[i][j]);
            }
            #pragma unroll
            for (int i = 0; i < 4; ++i) {
                const float sds = expf(acs_s[lt * 64 + ty + 16 * i]);
                #pragma unroll
                for (int j = 0; j < 4; ++j) yacc[i][j] = sds * oacc[i][j];
            }
        }
        __syncthreads();
        for (int st = 0; st <= lt; ++st) {
            #pragma unroll
            for (int e = 0; e < 16; ++e) {
                const int idx = e * 256 + tid;
                const int r = idx >> 6, cc = idx & 63;
                const size_t tg = rowbase + st * 64 + r;
                BX[r][cc] = Bmat[tg * kState + cc];
            }
            __syncthreads();
            float sacc[4][4] = {};
            for (int n = 0; n < kState; ++n) {
                float cv[4], bv[4];
                #pragma unroll
                for (int i = 0; i < 4; ++i) cv[i] = Cs[ty + 16 * i][n];
                #pragma unroll
                for (int j = 0; j < 4; ++j) bv[j] = BX[tx + 16 * j][n];
                #pragma unroll
                for (int i = 0; i < 4; ++i)
                    #pragma unroll
                    for (int j = 0; j < 4; ++j)
                        sacc[i][j] = fmaf(cv[i], bv[j], sacc[i][j]);
            }
            __syncthreads();
            #pragma unroll
            for (int i = 0; i < 4; ++i) {
                const int li = lt * 64 + ty + 16 * i;
                #pragma unroll
                for (int j = 0; j < 4; ++j) {
                    const int sj = st * 64 + tx + 16 * j;
                    Ss[ty + 16 * i][tx + 16 * j] =
                        (sj <= li) ? sacc[i][j] * expf(acs_s[li] - acs_s[sj]) : 0.f;
                }
            }
            #pragma unroll
            for (int e = 0; e < 16; ++e) {
                const int idx = e * 256 + tid;
                const int r = idx >> 6, cc = idx & 63;
                const size_t tg = rowbase + st * 64 + r;
                BX[r][cc] = x[tg * kDModel + hi * kP + cc] * dtm[tg * kHeads + hi];
            }
            __syncthreads();
            for (int s = 0; s < 64; ++s) {
                float sv[4], xv[4];
                #pragma unroll
                for (int i = 0; i < 4; ++i) sv[i] = Ss[ty + 16 * i][s];
                #pragma unroll
                for (int j = 0; j < 4; ++j) xv[j] = BX[s][tx + 16 * j];
                #pragma unroll
                for (int i = 0; i < 4; ++i)
                    #pragma unroll
                    for (int j = 0; j < 4; ++j)
                        yacc[i][j] = fmaf(sv[i], xv[j], yacc[i][j]);
            }
            __syncthreads();
        }
        #pragma unroll
        for (int i = 0; i < 4; ++i) {
            const int li = lt * 64 + ty + 16 * i;
            const size_t tg = rowbase + li;
            #pragma unroll
            for (int j = 0; j < 4; ++j) {
                const int pj = tx + 16 * j;
                const float v = yacc[i][j] + Dh * x[tg * kDModel + hi * kP + pj];
                Y[tg * kDModel + hi * kP + pj] = (bf16_t)__float2bfloat16(v);
            }
        }
    }
}

extern "C" void kernel_launch(void* const* d_in, const int* in_sizes, int n_in,
                              void* d_out, int out_size, void* d_ws, size_t ws_size,
                              hipStream_t stream)
{
    (void)in_sizes; (void)n_in; (void)out_size; (void)ws_size;
    const float* x     = (const float*)d_in[0];
    const float* A_log = (const float*)d_in[1];
    const float* Dvec  = (const float*)d_in[2];
    const float* B_w   = (const float*)d_in[3];
    const float* B_b   = (const float*)d_in[4];
    const float* C_w   = (const float*)d_in[5];
    const float* C_b   = (const float*)d_in[6];
    const float* dt_w  = (const float*)d_in[7];
    const float* dt_b  = (const float*)d_in[8];
    const float* out_w = (const float*)d_in[9];
    const float* out_b = (const float*)d_in[10];
    float* out = (float*)d_out;

    // workspace layout
    float* ws = (float*)d_ws;
    float* Bmat   = ws;                                                  // 2*4096*64
    float* Cmat   = Bmat + (size_t)kBatch * kSeq * kState;
    float* dtm    = Cmat + (size_t)kBatch * kSeq * kState;               // 2*4096*32
    float* Acs    = dtm + (size_t)kBatch * kSeq * kHeads;                // 2*32*16*256
    float* states = Acs + (size_t)kBatch * kHeads * kNChunk * kChunk;    // 2*16*32*64*64
    float* prevs  = states + (size_t)kBatch * kNChunk * kHeads * kP * kState;
    bf16_t* Y     = (bf16_t*)(prevs + (size_t)kBatch * kNChunk * kHeads * kP * kState);
    bf16_t* xb    = Y + (size_t)kM * kDModel;        // bf16 x
    bf16_t* wcat  = xb + (size_t)kM * kDModel;       // bf16 [256,2048] B/C/dt weights
    bf16_t* wob   = wcat + (size_t)256 * kDModel;    // bf16 out_w [2048,2048]

    const dim3 blk(256);
    // dtype converts
    cvt_bf16_kernel<<<dim3(kM * kDModel / 1024), blk, 0, stream>>>(x, xb, kM * kDModel);
    cvt_bf16_kernel<<<dim3(kDModel * kDModel / 1024), blk, 0, stream>>>(out_w, wob, kDModel * kDModel);
    pack_w_kernel<<<dim3(256 * kDModel / 256), blk, 0, stream>>>(B_w, C_w, dt_w, wcat);
    // fused B/C/dt projection (MFMA): grid (256/128, 8192/128)
    gemm_mfma<1><<<dim3(2, kM / 128), blk, 0, stream>>>(xb, wcat, kDModel, 0,
                                                        B_b, C_b, dt_b, Bmat, Cmat, dtm);
    // per-chunk cumulative decay
    dtcumsum_kernel<<<dim3(kBatch * kHeads * kNChunk), dim3(kChunk), 0, stream>>>(dtm, A_log, Acs);
    // per-chunk end states
    states_kernel<<<dim3(kBatch * kNChunk * kHeads), blk, 0, stream>>>(x, dtm, Bmat, Acs, states);
    // inter-chunk recurrence (16 steps)
    chunkscan_kernel<<<dim3(kBatch * kHeads), blk, 0, stream>>>(states, Acs, prevs);
    // intra-chunk Y (diag + off + D*x), bf16 staging
    ychunk_kernel<<<dim3(kBatch * kNChunk * kHeads), blk, 0, stream>>>(x, dtm, Bmat, Cmat, Acs, prevs, Dvec, Y);
    // out-projection (MFMA): grid (2048/128, 8192/128)
    gemm_mfma<0><<<dim3(kDModel / 128, kM / 128), blk, 0, stream>>>(Y, wob, kDModel, kDModel,
                                                                    out_b, nullptr, nullptr,
                                                                    out, nullptr, nullptr);
}

// Round 3
// 468.138 us; speedup vs baseline: 3.9763x; 1.4688x over previous
//
#include <hip/hip_runtime.h>
#include <hip/hip_bf16.h>
#include <math.h>

namespace {
constexpr int kDModel = 2048;
constexpr int kHeads  = 32;
constexpr int kState  = 64;
constexpr int kP      = 64;    // head dim = D_MODEL / N_HEADS
constexpr int kChunk  = 256;
constexpr int kNChunk = 16;    // SEQLEN / CHUNK
constexpr int kBatch  = 2;
constexpr int kSeq    = 4096;
constexpr int kM      = kBatch * kSeq;  // 8192 rows
}

typedef __bf16 bf16_t;
typedef __attribute__((ext_vector_type(8))) __bf16 bf16x8;
typedef __attribute__((ext_vector_type(4))) float f32x4;

__device__ __forceinline__ void gload_lds16(const void* g, void* l) {
    __builtin_amdgcn_global_load_lds(
        (const __attribute__((address_space(1))) void*)g,
        (__attribute__((address_space(3))) void*)l,
        16, 0, 0);
}

__device__ __forceinline__ short f2bs(float f) {
    __bf16 h = (__bf16)f;
    return __builtin_bit_cast(short, h);
}

// ---------------------------------------------------------------------------
// MFMA bf16 GEMM: C[M,N] = A[M,K] @ W[N,K]^T (+bias). 128x128 tile, BK=32,
// 256 threads = 4 waves in 2x2, each wave 64x64 via 4x4 of 16x16x32 MFMAs.
// MODE 0: plain, store o0[M x N] + b0.  MODE 1: BCdt split epilogue.
// ---------------------------------------------------------------------------
template <int MODE>
__global__ __launch_bounds__(256)
void gemm_mfma(const bf16_t* __restrict__ A, const bf16_t* __restrict__ W,
               int K, int N,
               const float* __restrict__ b0, const float* __restrict__ b1,
               const float* __restrict__ b2,
               float* __restrict__ o0, float* __restrict__ o1,
               float* __restrict__ o2)
{
    __shared__ short AstS[128 * 32];
    __shared__ short WstS[128 * 32];
    const int tid  = threadIdx.x;
    const int lane = tid & 63;
    const int wave = tid >> 6;
    const int wm = (wave >> 1) * 64;
    const int wn = (wave & 1) * 64;
    const int l15 = lane & 15, quad = lane >> 4;
    const int m0 = blockIdx.y * 128;
    const int n0 = blockIdx.x * 128;
    const int u0 = tid, u1 = tid + 256;   // 16B staging units

    f32x4 acc[4][4];
    #pragma unroll
    for (int i = 0; i < 4; ++i)
        #pragma unroll
        for (int j = 0; j < 4; ++j)
            acc[i][j] = (f32x4){0.f, 0.f, 0.f, 0.f};

    for (int k0 = 0; k0 < K; k0 += 32) {
        gload_lds16(A + (size_t)(m0 + (u0 >> 2)) * K + k0 + (u0 & 3) * 8, AstS + u0 * 8);
        gload_lds16(A + (size_t)(m0 + (u1 >> 2)) * K + k0 + (u1 & 3) * 8, AstS + u1 * 8);
        gload_lds16(W + (size_t)(n0 + (u0 >> 2)) * K + k0 + (u0 & 3) * 8, WstS + u0 * 8);
        gload_lds16(W + (size_t)(n0 + (u1 >> 2)) * K + k0 + (u1 & 3) * 8, WstS + u1 * 8);
        __syncthreads();
        bf16x8 af[4], bfr[4];
        #pragma unroll
        for (int mi = 0; mi < 4; ++mi)
            af[mi] = *reinterpret_cast<const bf16x8*>(&AstS[(wm + mi * 16 + l15) * 32 + quad * 8]);
        #pragma unroll
        for (int ni = 0; ni < 4; ++ni)
            bfr[ni] = *reinterpret_cast<const bf16x8*>(&WstS[(wn + ni * 16 + l15) * 32 + quad * 8]);
        #pragma unroll
        for (int mi = 0; mi < 4; ++mi)
            #pragma unroll
            for (int ni = 0; ni < 4; ++ni)
                acc[mi][ni] = __builtin_amdgcn_mfma_f32_16x16x32_bf16(
                    af[mi], bfr[ni], acc[mi][ni], 0, 0, 0);
        __syncthreads();
    }

    // C/D layout: col = lane&15, row = quad*4 + reg  [m89-verified]
    #pragma unroll
    for (int mi = 0; mi < 4; ++mi) {
        #pragma unroll
        for (int reg = 0; reg < 4; ++reg) {
            const int r = m0 + wm + mi * 16 + quad * 4 + reg;
            #pragma unroll
            for (int ni = 0; ni < 4; ++ni) {
                const float v = acc[mi][ni][reg];
                if (MODE == 0) {
                    const int c = n0 + wn + ni * 16 + l15;
                    o0[(size_t)r * N + c] = v + b0[c];
                } else {
                    const int n = n0 + wn + ni * 16 + l15;
                    if (n < 64) {
                        o0[(size_t)r * 64 + n] = v + b0[n];
                    } else if (n < 128) {
                        o1[(size_t)r * 64 + (n - 64)] = v + b1[n - 64];
                    } else if (n < 160) {
                        float z = v + b2[n - 128];
                        o2[(size_t)r * 32 + (n - 128)] = (z > 20.f) ? z : log1pf(expf(z));
                    }
                }
            }
        }
    }
}

// float -> bf16 convert, 4 elems/thread
__global__ __launch_bounds__(256)
void cvt_bf16_kernel(const float* __restrict__ src, bf16_t* __restrict__ dst, int n)
{
    const int i = (blockIdx.x * 256 + threadIdx.x) * 4;
    if (i + 3 < n) {
        const float4 v = *reinterpret_cast<const float4*>(src + i);
        dst[i + 0] = (bf16_t)v.x;
        dst[i + 1] = (bf16_t)v.y;
        dst[i + 2] = (bf16_t)v.z;
        dst[i + 3] = (bf16_t)v.w;
    }
}

// Concat [B_w;C_w;dt_w] into bf16 [256,2048], rows 160..255 zero
__global__ __launch_bounds__(256)
void pack_w_kernel(const float* __restrict__ B_w, const float* __restrict__ C_w,
                   const float* __restrict__ dt_w, bf16_t* __restrict__ wcat)
{
    const int idx = blockIdx.x * 256 + threadIdx.x;   // 256*2048 total
    const int r = idx >> 11, k = idx & 2047;
    float v = 0.f;
    if (r < 64)       v = B_w[r * 2048 + k];
    else if (r < 128) v = C_w[(r - 64) * 2048 + k];
    else if (r < 160) v = dt_w[(r - 128) * 2048 + k];
    wcat[idx] = (bf16_t)v;
}

// Per (b,h,chunk): Acs[l] = inclusive cumsum_l( dt[l] * A[h] ), A = -exp(A_log)
__global__ __launch_bounds__(kChunk)
void dtcumsum_kernel(const float* __restrict__ dtm, const float* __restrict__ A_log,
                     float* __restrict__ Acs)
{
    const int blk = blockIdx.x;                  // (bi*kHeads+hi)*kNChunk + ci
    const int ci = blk & (kNChunk - 1);
    const int hi = (blk >> 4) & (kHeads - 1);
    const int bi = blk >> 9;
    const int t = threadIdx.x;
    const float Ah = -expf(A_log[hi]);
    __shared__ float s[kChunk];
    s[t] = dtm[((size_t)bi * kSeq + ci * kChunk + t) * kHeads + hi] * Ah;
    __syncthreads();
    for (int off = 1; off < kChunk; off <<= 1) {
        const float add = (t >= off) ? s[t - off] : 0.f;
        __syncthreads();
        s[t] += add;
        __syncthreads();
    }
    Acs[((size_t)(bi * kHeads + hi) * kNChunk + ci) * kChunk + t] = s[t];
}

// states[b,c,h,p,n] = sum_l B[t,n] * exp(Acs[last]-Acs[l]) * x[t,h*64+p]*dt[t,h]
__global__ __launch_bounds__(256)
void states_kernel(const float* __restrict__ x, const float* __restrict__ dtm,
                   const float* __restrict__ Bmat, const float* __restrict__ Acs,
                   float* __restrict__ states)
{
    const int blk = blockIdx.x;                  // (bi*kNChunk+ci)*kHeads + hi
    const int hi = blk & (kHeads - 1);
    const int ci = (blk >> 5) & (kNChunk - 1);
    const int bi = blk >> 9;
    const float* acs = Acs + ((size_t)(bi * kHeads + hi) * kNChunk + ci) * kChunk;
    const float a_last = acs[kChunk - 1];
    __shared__ float Bs[32][kState];
    __shared__ float Xs[32][kP];
    const int tid = threadIdx.x;
    const int tx = tid & 15, ty = tid >> 4;
    float acc[4][4] = {};
    for (int l0 = 0; l0 < kChunk; l0 += 32) {
        #pragma unroll
        for (int e = 0; e < 8; ++e) {
            const int idx = e * 256 + tid;
            const int r = idx >> 6, cc = idx & 63;
            const size_t tg = (size_t)bi * kSeq + ci * kChunk + l0 + r;
            Bs[r][cc] = Bmat[tg * kState + cc];
            const float decay = expf(a_last - acs[l0 + r]);
            const float dtv = dtm[tg * kHeads + hi];
            Xs[r][cc] = x[tg * kDModel + hi * kP + cc] * dtv * decay;
        }
        __syncthreads();
        #pragma unroll
        for (int l = 0; l < 32; ++l) {
            float xv[4], bv[4];
            #pragma unroll
            for (int i = 0; i < 4; ++i) xv[i] = Xs[l][ty + 16 * i];
            #pragma unroll
            for (int j = 0; j < 4; ++j) bv[j] = Bs[l][tx + 16 * j];
            #pragma unroll
            for (int i = 0; i < 4; ++i)
                #pragma unroll
                for (int j = 0; j < 4; ++j)
                    acc[i][j] = fmaf(xv[i], bv[j], acc[i][j]);
        }
        __syncthreads();
    }
    float* sp = states + ((size_t)(bi * kNChunk + ci) * kHeads + hi) * (kP * kState);
    #pragma unroll
    for (int i = 0; i < 4; ++i)
        #pragma unroll
        for (int j = 0; j < 4; ++j)
            sp[(size_t)(ty + 16 * i) * kState + (tx + 16 * j)] = acc[i][j];
}

// prevs[b,0,h]=0 ; prevs[b,c,h] = exp(a[c-1])*prevs[b,c-1,h] + states[b,c-1,h]
__global__ __launch_bounds__(256)
void chunkscan_kernel(const float* __restrict__ states, const float* __restrict__ Acs,
                      float* __restrict__ prevs)
{
    const int hi = blockIdx.x & (kHeads - 1);
    const int bi = blockIdx.x >> 5;
    const int tid = threadIdx.x;
    __shared__ float ea[kNChunk];
    if (tid < kNChunk)
        ea[tid] = expf(Acs[((size_t)(bi * kHeads + hi) * kNChunk + tid) * kChunk + kChunk - 1]);
    __syncthreads();
    float P[16];
    {
        float* pp = prevs + ((size_t)(bi * kNChunk + 0) * kHeads + hi) * (kP * kState);
        #pragma unroll
        for (int e = 0; e < 16; ++e) { P[e] = 0.f; pp[e * 256 + tid] = 0.f; }
    }
    for (int c = 1; c < kNChunk; ++c) {
        const float* sp = states + ((size_t)(bi * kNChunk + (c - 1)) * kHeads + hi) * (kP * kState);
        float* pp = prevs + ((size_t)(bi * kNChunk + c) * kHeads + hi) * (kP * kState);
        const float e_ = ea[c - 1];
        #pragma unroll
        for (int e = 0; e < 16; ++e) {
            P[e] = fmaf(e_, P[e], sp[e * 256 + tid]);
            pp[e * 256 + tid] = P[e];
        }
    }
}

// ---------------------------------------------------------------------------
// MFMA intra-chunk Y. Block = (b,c,h,lt): one 64-row l-tile. 4 waves, wave w
// owns rows [w*16, w*16+16) of the tile. Two chained MFMAs per s-tile:
//   S = C_lt @ B_st^T  (C/D regs) -> decay/mask -> bf16 -> private LDS rows
//   Y += S' @ XdtT     (A-rows of S' == rows this wave just wrote: no barrier)
// Y_off = (C_lt @ P^T) * exp(acs[l]) seeds the accumulator.
// LDS stride 72 bf16 = 144 B: 16B-aligned ds_read_b128, 2-way banks (free).
// ---------------------------------------------------------------------------
__global__ __launch_bounds__(256)
void ychunk_mfma(const float* __restrict__ x, const float* __restrict__ dtm,
                 const float* __restrict__ Bmat, const float* __restrict__ Cmat,
                 const float* __restrict__ Acs, const float* __restrict__ prevs,
                 const float* __restrict__ Dvec, bf16_t* __restrict__ Y)
{
    const int blk = blockIdx.x;                  // ((bi*16+ci)*32+hi)*4 + lt
    const int lt = blk & 3;
    const int hi = (blk >> 2) & (kHeads - 1);
    const int ci = (blk >> 7) & (kNChunk - 1);
    const int bi = blk >> 11;
    __shared__ float acs_s[kChunk];
    __shared__ short Cs[64 * 72];
    __shared__ short Bs[64 * 72];
    __shared__ short Xt[64 * 72];   // XdtT[p][s]
    __shared__ short Sp[64 * 72];   // S' [l][s], per-wave private 16-row slices
    const int tid = threadIdx.x;
    const int lane = tid & 63;
    const int wave = tid >> 6;
    const int l15 = lane & 15, quad = lane >> 4;
    const size_t rowbase = (size_t)bi * kSeq + ci * kChunk;

    acs_s[tid] = Acs[((size_t)(bi * kHeads + hi) * kNChunk + ci) * kChunk + tid];
    // stage C l-tile and P (P -> Bs) as bf16
    const float* pp = prevs + ((size_t)(bi * kNChunk + ci) * kHeads + hi) * (kP * kState);
    #pragma unroll
    for (int e = 0; e < 4; ++e) {
        const int idx = e * 1024 + tid * 4;
        const int r = idx >> 6, c = idx & 63;
        const float4 vc = *reinterpret_cast<const float4*>(
            Cmat + (rowbase + lt * 64 + r) * kState + c);
        const float4 vp = *reinterpret_cast<const float4*>(pp + idx);
        short4 sc, sp4;
        sc.x = f2bs(vc.x); sc.y = f2bs(vc.y); sc.z = f2bs(vc.z); sc.w = f2bs(vc.w);
        sp4.x = f2bs(vp.x); sp4.y = f2bs(vp.y); sp4.z = f2bs(vp.z); sp4.w = f2bs(vp.w);
        *reinterpret_cast<short4*>(&Cs[r * 72 + c]) = sc;
        *reinterpret_cast<short4*>(&Bs[r * 72 + c]) = sp4;
    }
    __syncthreads();

    // A-frags (C rows of this wave's slice) — reused for Y_off and every S-tile
    bf16x8 af[2];
    af[0] = *reinterpret_cast<const bf16x8*>(&Cs[(wave * 16 + l15) * 72 + quad * 8]);
    af[1] = *reinterpret_cast<const bf16x8*>(&Cs[(wave * 16 + l15) * 72 + 32 + quad * 8]);

    // Y_off = (C @ P^T) * exp(acs[l])
    f32x4 yacc[4];
    #pragma unroll
    for (int ni = 0; ni < 4; ++ni) yacc[ni] = (f32x4){0.f, 0.f, 0.f, 0.f};
    #pragma unroll
    for (int ni = 0; ni < 4; ++ni) {
        const bf16x8 b0 = *reinterpret_cast<const bf16x8*>(&Bs[(ni * 16 + l15) * 72 + quad * 8]);
        const bf16x8 b1 = *reinterpret_cast<const bf16x8*>(&Bs[(ni * 16 + l15) * 72 + 32 + quad * 8]);
        yacc[ni] = __builtin_amdgcn_mfma_f32_16x16x32_bf16(af[0], b0, yacc[ni], 0, 0, 0);
        yacc[ni] = __builtin_amdgcn_mfma_f32_16x16x32_bf16(af[1], b1, yacc[ni], 0, 0, 0);
    }
    const int mrow = wave * 16 + quad * 4;   // C/D: row = quad*4+reg within 16x16
    {
        float es[4];
        #pragma unroll
        for (int reg = 0; reg < 4; ++reg) es[reg] = expf(acs_s[lt * 64 + mrow + reg]);
        #pragma unroll
        for (int ni = 0; ni < 4; ++ni)
            #pragma unroll
            for (int reg = 0; reg < 4; ++reg) yacc[ni][reg] *= es[reg];
    }

    for (int st = 0; st <= lt; ++st) {
        __syncthreads();   // everyone done reading Bs/Xt from previous stage
        // stage B s-tile
        #pragma unroll
        for (int e = 0; e < 4; ++e) {
            const int idx = e * 1024 + tid * 4;
            const int r = idx >> 6, c = idx & 63;
            const float4 v = *reinterpret_cast<const float4*>(
                Bmat + (rowbase + st * 64 + r) * kState + c);
            short4 s4;
            s4.x = f2bs(v.x); s4.y = f2bs(v.y); s4.z = f2bs(v.z); s4.w = f2bs(v.w);
            *reinterpret_cast<short4*>(&Bs[r * 72 + c]) = s4;
        }
        // stage XdtT[p][s]
        #pragma unroll
        for (int e = 0; e < 16; ++e) {
            const int idx = e * 256 + tid;
            const int s = idx >> 6, p = idx & 63;
            const size_t tg = rowbase + st * 64 + s;
            Xt[p * 72 + s] = f2bs(x[tg * kDModel + hi * kP + p] * dtm[tg * kHeads + hi]);
        }
        __syncthreads();
        // S = C_lt(slice) @ B_st^T
        f32x4 sacc[4];
        #pragma unroll
        for (int ni = 0; ni < 4; ++ni) sacc[ni] = (f32x4){0.f, 0.f, 0.f, 0.f};
        #pragma unroll
        for (int ni = 0; ni < 4; ++ni) {
            const bf16x8 b0 = *reinterpret_cast<const bf16x8*>(&Bs[(ni * 16 + l15) * 72 + quad * 8]);
            const bf16x8 b1 = *reinterpret_cast<const bf16x8*>(&Bs[(ni * 16 + l15) * 72 + 32 + quad * 8]);
            sacc[ni] = __builtin_amdgcn_mfma_f32_16x16x32_bf16(af[0], b0, sacc[ni], 0, 0, 0);
            sacc[ni] = __builtin_amdgcn_mfma_f32_16x16x32_bf16(af[1], b1, sacc[ni], 0, 0, 0);
        }
        // decay + causal mask (only the st==lt diagonal needs masking), -> S' bf16
        #pragma unroll
        for (int reg = 0; reg < 4; ++reg) {
            const int l = lt * 64 + mrow + reg;
            const float al = acs_s[l];
            #pragma unroll
            for (int ni = 0; ni < 4; ++ni) {
                const int scol = ni * 16 + l15;
                const int sg = st * 64 + scol;
                float v = sacc[ni][reg] * expf(al - acs_s[sg]);
                if (st == lt && sg > l) v = 0.f;
                Sp[(mrow + reg) * 72 + scol] = f2bs(v);
            }
        }
        // Y += S' @ XdtT  (A rows are this wave's own just-written slice)
        const bf16x8 as0 = *reinterpret_cast<const bf16x8*>(&Sp[(wave * 16 + l15) * 72 + quad * 8]);
        const bf16x8 as1 = *reinterpret_cast<const bf16x8*>(&Sp[(wave * 16 + l15) * 72 + 32 + quad * 8]);
        #pragma unroll
        for (int ni = 0; ni < 4; ++ni) {
            const bf16x8 x0 = *reinterpret_cast<const bf16x8*>(&Xt[(ni * 16 + l15) * 72 + quad * 8]);
            const bf16x8 x1 = *reinterpret_cast<const bf16x8*>(&Xt[(ni * 16 + l15) * 72 + 32 + quad * 8]);
            yacc[ni] = __builtin_amdgcn_mfma_f32_16x16x32_bf16(as0, x0, yacc[ni], 0, 0, 0);
            yacc[ni] = __builtin_amdgcn_mfma_f32_16x16x32_bf16(as1, x1, yacc[ni], 0, 0, 0);
        }
    }

    // epilogue: += D*x, store bf16 Y
    const float Dh = Dvec[hi];
    #pragma unroll
    for (int reg = 0; reg < 4; ++reg) {
        const size_t tg = rowbase + lt * 64 + mrow + reg;
        #pragma unroll
        for (int ni = 0; ni < 4; ++ni) {
            const int p = ni * 16 + l15;
            const float v = yacc[ni][reg] + Dh * x[tg * kDModel + hi * kP + p];
            Y[tg * kDModel + hi * kP + p] = (bf16_t)v;
        }
    }
}

extern "C" void kernel_launch(void* const* d_in, const int* in_sizes, int n_in,
                              void* d_out, int out_size, void* d_ws, size_t ws_size,
                              hipStream_t stream)
{
    (void)in_sizes; (void)n_in; (void)out_size; (void)ws_size;
    const float* x     = (const float*)d_in[0];
    const float* A_log = (const float*)d_in[1];
    const float* Dvec  = (const float*)d_in[2];
    const float* B_w   = (const float*)d_in[3];
    const float* B_b   = (const float*)d_in[4];
    const float* C_w   = (const float*)d_in[5];
    const float* C_b   = (const float*)d_in[6];
    const float* dt_w  = (const float*)d_in[7];
    const float* dt_b  = (const float*)d_in[8];
    const float* out_w = (const float*)d_in[9];
    const float* out_b = (const float*)d_in[10];
    float* out = (float*)d_out;

    // workspace layout
    float* ws = (float*)d_ws;
    float* Bmat   = ws;                                                  // 2*4096*64
    float* Cmat   = Bmat + (size_t)kBatch * kSeq * kState;
    float* dtm    = Cmat + (size_t)kBatch * kSeq * kState;               // 2*4096*32
    float* Acs    = dtm + (size_t)kBatch * kSeq * kHeads;                // 2*32*16*256
    float* states = Acs + (size_t)kBatch * kHeads * kNChunk * kChunk;    // 2*16*32*64*64
    float* prevs  = states + (size_t)kBatch * kNChunk * kHeads * kP * kState;
    bf16_t* Y     = (bf16_t*)(prevs + (size_t)kBatch * kNChunk * kHeads * kP * kState);
    bf16_t* xb    = Y + (size_t)kM * kDModel;        // bf16 x
    bf16_t* wcat  = xb + (size_t)kM * kDModel;       // bf16 [256,2048] B/C/dt weights
    bf16_t* wob   = wcat + (size_t)256 * kDModel;    // bf16 out_w [2048,2048]

    const dim3 blk(256);
    // dtype converts
    cvt_bf16_kernel<<<dim3(kM * kDModel / 1024), blk, 0, stream>>>(x, xb, kM * kDModel);
    cvt_bf16_kernel<<<dim3(kDModel * kDModel / 1024), blk, 0, stream>>>(out_w, wob, kDModel * kDModel);
    pack_w_kernel<<<dim3(256 * kDModel / 256), blk, 0, stream>>>(B_w, C_w, dt_w, wcat);
    // fused B/C/dt projection (MFMA)
    gemm_mfma<1><<<dim3(2, kM / 128), blk, 0, stream>>>(xb, wcat, kDModel, 0,
                                                        B_b, C_b, dt_b, Bmat, Cmat, dtm);
    // per-chunk cumulative decay
    dtcumsum_kernel<<<dim3(kBatch * kHeads * kNChunk), dim3(kChunk), 0, stream>>>(dtm, A_log, Acs);
    // per-chunk end states
    states_kernel<<<dim3(kBatch * kNChunk * kHeads), blk, 0, stream>>>(x, dtm, Bmat, Acs, states);
    // inter-chunk recurrence (16 steps)
    chunkscan_kernel<<<dim3(kBatch * kHeads), blk, 0, stream>>>(states, Acs, prevs);
    // intra-chunk Y (MFMA): grid (b,c,h,lt)
    ychunk_mfma<<<dim3(kBatch * kNChunk * kHeads * 4), blk, 0, stream>>>(
        x, dtm, Bmat, Cmat, Acs, prevs, Dvec, Y);
    // out-projection (MFMA)
    gemm_mfma<0><<<dim3(kDModel / 128, kM / 128), blk, 0, stream>>>(Y, wob, kDModel, kDModel,
                                                                    out_b, nullptr, nullptr,
                                                                    out, nullptr, nullptr);
}

// Round 5
// 418.557 us; speedup vs baseline: 4.4473x; 1.1185x over previous
//
#include <hip/hip_runtime.h>
#include <hip/hip_bf16.h>
#include <math.h>

namespace {
constexpr int kDModel = 2048;
constexpr int kHeads  = 32;
constexpr int kState  = 64;
constexpr int kP      = 64;    // head dim = D_MODEL / N_HEADS
constexpr int kChunk  = 256;
constexpr int kNChunk = 16;    // SEQLEN / CHUNK
constexpr int kBatch  = 2;
constexpr int kSeq    = 4096;
constexpr int kM      = kBatch * kSeq;  // 8192 rows
}

typedef __bf16 bf16_t;
typedef __attribute__((ext_vector_type(8))) __bf16 bf16x8;
typedef __attribute__((ext_vector_type(4))) __bf16 bf16x4;
typedef __attribute__((ext_vector_type(4))) float f32x4;

__device__ __forceinline__ void gload_lds16(const void* g, void* l) {
    __builtin_amdgcn_global_load_lds(
        (const __attribute__((address_space(1))) void*)g,
        (__attribute__((address_space(3))) void*)l,
        16, 0, 0);
}

// ---------------------------------------------------------------------------
// MFMA bf16 GEMM: C[M,N] = A[M,K] @ W[N,K]^T (+bias). 128x128 tile, BK=32,
// 256 threads = 4 waves in 2x2, each wave 64x64 via 4x4 of 16x16x32 MFMAs.
// MODE 0: fp32 store o0f[M x N] + b0.  MODE 1: BCdt split epilogue ->
//   bf16 B (o0h), bf16 C (o1h), fp32 softplus dt (o2f).
// ---------------------------------------------------------------------------
template <int MODE>
__global__ __launch_bounds__(256)
void gemm_mfma(const bf16_t* __restrict__ A, const bf16_t* __restrict__ W,
               int K, int N,
               const float* __restrict__ b0, const float* __restrict__ b1,
               const float* __restrict__ b2,
               float* __restrict__ o0f, bf16_t* __restrict__ o0h,
               bf16_t* __restrict__ o1h, float* __restrict__ o2f)
{
    __shared__ __bf16 AstS[128 * 32];
    __shared__ __bf16 WstS[128 * 32];
    const int tid  = threadIdx.x;
    const int lane = tid & 63;
    const int wave = tid >> 6;
    const int wm = (wave >> 1) * 64;
    const int wn = (wave & 1) * 64;
    const int l15 = lane & 15, quad = lane >> 4;
    const int m0 = blockIdx.y * 128;
    const int n0 = blockIdx.x * 128;
    const int u0 = tid, u1 = tid + 256;   // 16B staging units

    f32x4 acc[4][4];
    #pragma unroll
    for (int i = 0; i < 4; ++i)
        #pragma unroll
        for (int j = 0; j < 4; ++j)
            acc[i][j] = (f32x4){0.f, 0.f, 0.f, 0.f};

    for (int k0 = 0; k0 < K; k0 += 32) {
        gload_lds16(A + (size_t)(m0 + (u0 >> 2)) * K + k0 + (u0 & 3) * 8, AstS + u0 * 8);
        gload_lds16(A + (size_t)(m0 + (u1 >> 2)) * K + k0 + (u1 & 3) * 8, AstS + u1 * 8);
        gload_lds16(W + (size_t)(n0 + (u0 >> 2)) * K + k0 + (u0 & 3) * 8, WstS + u0 * 8);
        gload_lds16(W + (size_t)(n0 + (u1 >> 2)) * K + k0 + (u1 & 3) * 8, WstS + u1 * 8);
        __syncthreads();
        bf16x8 af[4], bfr[4];
        #pragma unroll
        for (int mi = 0; mi < 4; ++mi)
            af[mi] = *reinterpret_cast<const bf16x8*>(&AstS[(wm + mi * 16 + l15) * 32 + quad * 8]);
        #pragma unroll
        for (int ni = 0; ni < 4; ++ni)
            bfr[ni] = *reinterpret_cast<const bf16x8*>(&WstS[(wn + ni * 16 + l15) * 32 + quad * 8]);
        #pragma unroll
        for (int mi = 0; mi < 4; ++mi)
            #pragma unroll
            for (int ni = 0; ni < 4; ++ni)
                acc[mi][ni] = __builtin_amdgcn_mfma_f32_16x16x32_bf16(
                    af[mi], bfr[ni], acc[mi][ni], 0, 0, 0);
        __syncthreads();
    }

    // C/D layout: col = lane&15, row = quad*4 + reg  [m89-verified]
    #pragma unroll
    for (int mi = 0; mi < 4; ++mi) {
        #pragma unroll
        for (int reg = 0; reg < 4; ++reg) {
            const int r = m0 + wm + mi * 16 + quad * 4 + reg;
            #pragma unroll
            for (int ni = 0; ni < 4; ++ni) {
                const float v = acc[mi][ni][reg];
                if (MODE == 0) {
                    const int c = n0 + wn + ni * 16 + l15;
                    o0f[(size_t)r * N + c] = v + b0[c];
                } else {
                    const int n = n0 + wn + ni * 16 + l15;
                    if (n < 64) {
                        o0h[(size_t)r * 64 + n] = (bf16_t)(v + b0[n]);
                    } else if (n < 128) {
                        o1h[(size_t)r * 64 + (n - 64)] = (bf16_t)(v + b1[n - 64]);
                    } else if (n < 160) {
                        float z = v + b2[n - 128];
                        o2f[(size_t)r * 32 + (n - 128)] = (z > 20.f) ? z : log1pf(expf(z));
                    }
                }
            }
        }
    }
}

// float -> bf16 convert, 4 elems/thread
__global__ __launch_bounds__(256)
void cvt_bf16_kernel(const float* __restrict__ src, bf16_t* __restrict__ dst, int n)
{
    const int i = (blockIdx.x * 256 + threadIdx.x) * 4;
    if (i + 3 < n) {
        const float4 v = *reinterpret_cast<const float4*>(src + i);
        dst[i + 0] = (bf16_t)v.x;
        dst[i + 1] = (bf16_t)v.y;
        dst[i + 2] = (bf16_t)v.z;
        dst[i + 3] = (bf16_t)v.w;
    }
}

// Concat [B_w;C_w;dt_w] into bf16 [256,2048], rows 160..255 zero
__global__ __launch_bounds__(256)
void pack_w_kernel(const float* __restrict__ B_w, const float* __restrict__ C_w,
                   const float* __restrict__ dt_w, bf16_t* __restrict__ wcat)
{
    const int idx = blockIdx.x * 256 + threadIdx.x;   // 256*2048 total
    const int r = idx >> 11, k = idx & 2047;
    float v = 0.f;
    if (r < 64)       v = B_w[r * 2048 + k];
    else if (r < 128) v = C_w[(r - 64) * 2048 + k];
    else if (r < 160) v = dt_w[(r - 128) * 2048 + k];
    wcat[idx] = (bf16_t)v;
}

// Per (b,h,chunk): Acs[l] = inclusive cumsum_l( dt[l] * A[h] ), A = -exp(A_log)
__global__ __launch_bounds__(kChunk)
void dtcumsum_kernel(const float* __restrict__ dtm, const float* __restrict__ A_log,
                     float* __restrict__ Acs)
{
    const int blk = blockIdx.x;                  // (bi*kHeads+hi)*kNChunk + ci
    const int ci = blk & (kNChunk - 1);
    const int hi = (blk >> 4) & (kHeads - 1);
    const int bi = blk >> 9;
    const int t = threadIdx.x;
    const float Ah = -expf(A_log[hi]);
    __shared__ float s[kChunk];
    s[t] = dtm[((size_t)bi * kSeq + ci * kChunk + t) * kHeads + hi] * Ah;
    __syncthreads();
    for (int off = 1; off < kChunk; off <<= 1) {
        const float add = (t >= off) ? s[t - off] : 0.f;
        __syncthreads();
        s[t] += add;
        __syncthreads();
    }
    Acs[((size_t)(bi * kHeads + hi) * kNChunk + ci) * kChunk + t] = s[t];
}

// Transpose one chunk of B: bTg[b,c][n][l] = Bb16[(b,c,l)][n]
__global__ __launch_bounds__(256)
void bT_kernel(const bf16_t* __restrict__ Bb16, bf16_t* __restrict__ bTg)
{
    const int ci = blockIdx.x & (kNChunk - 1);
    const int bi = blockIdx.x >> 4;
    const size_t rowbase = (size_t)bi * kSeq + ci * kChunk;
    __shared__ __bf16 T[64 * 264];
    const int tid = threadIdx.x;        // = row l
    bf16x8 v[8];
    #pragma unroll
    for (int e = 0; e < 8; ++e)
        v[e] = *reinterpret_cast<const bf16x8*>(Bb16 + (rowbase + tid) * 64 + e * 8);
    #pragma unroll
    for (int e = 0; e < 8; ++e)
        #pragma unroll
        for (int j = 0; j < 8; ++j)
            T[(e * 8 + j) * 264 + tid] = v[e][j];
    __syncthreads();
    const int n = tid >> 2, seg = (tid & 3) * 64;
    bf16_t* dst = bTg + ((size_t)(bi * kNChunk + ci)) * (64 * 256) + n * 256 + seg;
    #pragma unroll
    for (int j = 0; j < 8; ++j) {
        *reinterpret_cast<bf16x8*>(dst + j * 8) =
            *reinterpret_cast<const bf16x8*>(&T[n * 264 + seg + j * 8]);
    }
}

// xdtT[(b,c,h)][p][l] = bf16( xb[t, h*64+p] * dt[t,h] ),  t = rowbase+l
__global__ __launch_bounds__(256)
void xdtT_kernel(const bf16_t* __restrict__ xb, const float* __restrict__ dtm,
                 bf16_t* __restrict__ xdtT)
{
    const int blk = blockIdx.x;                  // (bi*16+ci)*32+hi
    const int hi = blk & (kHeads - 1);
    const int ci = (blk >> 5) & (kNChunk - 1);
    const int bi = blk >> 9;
    const size_t rowbase = (size_t)bi * kSeq + ci * kChunk;
    __shared__ __bf16 T[64 * 264];
    const int tid = threadIdx.x;        // = row l
    const float d = dtm[(rowbase + tid) * kHeads + hi];
    bf16x8 v[8];
    #pragma unroll
    for (int e = 0; e < 8; ++e)
        v[e] = *reinterpret_cast<const bf16x8*>(xb + (rowbase + tid) * kDModel + hi * kP + e * 8);
    #pragma unroll
    for (int e = 0; e < 8; ++e)
        #pragma unroll
        for (int j = 0; j < 8; ++j)
            T[(e * 8 + j) * 264 + tid] = (__bf16)((float)v[e][j] * d);
    __syncthreads();
    const int p = tid >> 2, seg = (tid & 3) * 64;
    bf16_t* dst = xdtT + (size_t)blk * (64 * 256) + p * 256 + seg;
    #pragma unroll
    for (int j = 0; j < 8; ++j) {
        *reinterpret_cast<bf16x8*>(dst + j * 8) =
            *reinterpret_cast<const bf16x8*>(&T[p * 264 + seg + j * 8]);
    }
}

// ---------------------------------------------------------------------------
// MFMA chunk states: states[(b,c,h)][p][n] = sum_l xdtT[p][l]*dec[l]*B[l][n]
// A = decayed xdtT slice [p][l] (64x256), B-op = bTg [n][l] (64x256), K=256.
// ---------------------------------------------------------------------------
__global__ __launch_bounds__(256)
void states_mfma(const bf16_t* __restrict__ xdtT, const bf16_t* __restrict__ bTg,
                 const float* __restrict__ Acs, float* __restrict__ states)
{
    const int blk = blockIdx.x;                  // (bi*16+ci)*32+hi
    const int hi = blk & (kHeads - 1);
    const int ci = (blk >> 5) & (kNChunk - 1);
    const int bi = blk >> 9;
    __shared__ __bf16 Xa[64 * 264];
    __shared__ __bf16 Bt[64 * 264];
    __shared__ float dec[kChunk];
    const int tid = threadIdx.x;
    const int lane = tid & 63;
    const int wave = tid >> 6;
    const int l15 = lane & 15, quad = lane >> 4;

    const float* acs = Acs + ((size_t)(bi * kHeads + hi) * kNChunk + ci) * kChunk;
    dec[tid] = expf(acs[kChunk - 1] - acs[tid]);   // <= 1
    __syncthreads();

    const bf16_t* bsrc = bTg + ((size_t)(bi * kNChunk + ci)) * (64 * 256);
    const bf16_t* xsrc = xdtT + (size_t)blk * (64 * 256);
    #pragma unroll
    for (int e = 0; e < 8; ++e) {
        const int u = e * 256 + tid;
        const int r = u >> 5, seg = (u & 31) * 8;
        *reinterpret_cast<bf16x8*>(&Bt[r * 264 + seg]) =
            *reinterpret_cast<const bf16x8*>(bsrc + r * 256 + seg);
        bf16x8 xv = *reinterpret_cast<const bf16x8*>(xsrc + r * 256 + seg);
        bf16x8 xo;
        #pragma unroll
        for (int j = 0; j < 8; ++j)
            xo[j] = (__bf16)((float)xv[j] * dec[seg + j]);
        *reinterpret_cast<bf16x8*>(&Xa[r * 264 + seg]) = xo;
    }
    __syncthreads();

    f32x4 acc[4];
    #pragma unroll
    for (int ni = 0; ni < 4; ++ni) acc[ni] = (f32x4){0.f, 0.f, 0.f, 0.f};
    #pragma unroll
    for (int kk = 0; kk < 8; ++kk) {
        const bf16x8 af = *reinterpret_cast<const bf16x8*>(
            &Xa[(wave * 16 + l15) * 264 + kk * 32 + quad * 8]);
        #pragma unroll
        for (int ni = 0; ni < 4; ++ni) {
            const bf16x8 bf = *reinterpret_cast<const bf16x8*>(
                &Bt[(ni * 16 + l15) * 264 + kk * 32 + quad * 8]);
            acc[ni] = __builtin_amdgcn_mfma_f32_16x16x32_bf16(af, bf, acc[ni], 0, 0, 0);
        }
    }
    float* sp = states + (size_t)blk * (kP * kState);
    #pragma unroll
    for (int reg = 0; reg < 4; ++reg) {
        const int p = wave * 16 + quad * 4 + reg;
        #pragma unroll
        for (int ni = 0; ni < 4; ++ni)
            sp[(size_t)p * kState + ni * 16 + l15] = acc[ni][reg];
    }
}

// prevs[b,0,h]=0 ; prevs[b,c,h] = exp(a[c-1])*prevs[b,c-1,h] + states[b,c-1,h]
__global__ __launch_bounds__(256)
void chunkscan_kernel(const float* __restrict__ states, const float* __restrict__ Acs,
                      float* __restrict__ prevs)
{
    const int hi = blockIdx.x & (kHeads - 1);
    const int bi = blockIdx.x >> 5;
    const int tid = threadIdx.x;
    __shared__ float ea[kNChunk];
    if (tid < kNChunk)
        ea[tid] = expf(Acs[((size_t)(bi * kHeads + hi) * kNChunk + tid) * kChunk + kChunk - 1]);
    __syncthreads();
    float P[16];
    {
        float* pp = prevs + ((size_t)(bi * kNChunk + 0) * kHeads + hi) * (kP * kState);
        #pragma unroll
        for (int e = 0; e < 16; ++e) { P[e] = 0.f; pp[e * 256 + tid] = 0.f; }
    }
    for (int c = 1; c < kNChunk; ++c) {
        const float* sp = states + ((size_t)(bi * kNChunk + (c - 1)) * kHeads + hi) * (kP * kState);
        float* pp = prevs + ((size_t)(bi * kNChunk + c) * kHeads + hi) * (kP * kState);
        const float e_ = ea[c - 1];
        #pragma unroll
        for (int e = 0; e < 16; ++e) {
            P[e] = fmaf(e_, P[e], sp[e * 256 + tid]);
            pp[e * 256 + tid] = P[e];
        }
    }
}

// ---------------------------------------------------------------------------
// MFMA intra-chunk Y. Block = (b,c,h,lt). All LDS arrays are __bf16 with
// type-consistent accesses; explicit barrier between S' write and read.
// ---------------------------------------------------------------------------
__global__ __launch_bounds__(256)
void ychunk_mfma(const float* __restrict__ x, const bf16_t* __restrict__ Bb16,
                 const bf16_t* __restrict__ Cb16, const bf16_t* __restrict__ xdtT,
                 const float* __restrict__ Acs, const float* __restrict__ prevs,
                 const float* __restrict__ Dvec, bf16_t* __restrict__ Y)
{
    const int blk = blockIdx.x;                  // ((bi*16+ci)*32+hi)*4 + lt
    const int lt = blk & 3;
    const int hi = (blk >> 2) & (kHeads - 1);
    const int ci = (blk >> 7) & (kNChunk - 1);
    const int bi = blk >> 11;
    __shared__ float acs_s[kChunk];
    __shared__ __bf16 Cs[64 * 72];
    __shared__ __bf16 Bs[64 * 72];
    __shared__ __bf16 Xt[64 * 72];   // XdtT[p][s]
    __shared__ __bf16 Sp[64 * 72];   // S' [l][s]
    const int tid = threadIdx.x;
    const int lane = tid & 63;
    const int wave = tid >> 6;
    const int l15 = lane & 15, quad = lane >> 4;
    const size_t rowbase = (size_t)bi * kSeq + ci * kChunk;
    const bf16_t* xdsrc = xdtT + ((size_t)((bi * kNChunk + ci) * kHeads + hi)) * (64 * 256);

    acs_s[tid] = Acs[((size_t)(bi * kHeads + hi) * kNChunk + ci) * kChunk + tid];
    // stage C l-tile (vec copy) and P (fp32 -> bf16) into Bs
    #pragma unroll
    for (int e = 0; e < 2; ++e) {
        const int u = e * 256 + tid;
        const int r = u >> 3, seg = (u & 7) * 8;
        *reinterpret_cast<bf16x8*>(&Cs[r * 72 + seg]) =
            *reinterpret_cast<const bf16x8*>(Cb16 + (rowbase + lt * 64 + r) * 64 + seg);
    }
    const float* pp = prevs + ((size_t)(bi * kNChunk + ci) * kHeads + hi) * (kP * kState);
    #pragma unroll
    for (int e = 0; e < 4; ++e) {
        const int idx = e * 1024 + tid * 4;
        const int r = idx >> 6, c = idx & 63;
        const float4 vp = *reinterpret_cast<const float4*>(pp + idx);
        bf16x4 p4;
        p4[0] = (__bf16)vp.x; p4[1] = (__bf16)vp.y;
        p4[2] = (__bf16)vp.z; p4[3] = (__bf16)vp.w;
        *reinterpret_cast<bf16x4*>(&Bs[r * 72 + c]) = p4;
    }
    __syncthreads();

    // A-frags (C rows of this wave's slice) — reused for Y_off and every S-tile
    bf16x8 af[2];
    af[0] = *reinterpret_cast<const bf16x8*>(&Cs[(wave * 16 + l15) * 72 + quad * 8]);
    af[1] = *reinterpret_cast<const bf16x8*>(&Cs[(wave * 16 + l15) * 72 + 32 + quad * 8]);

    // Y_off = (C @ P^T) * exp(acs[l])
    f32x4 yacc[4];
    #pragma unroll
    for (int ni = 0; ni < 4; ++ni) yacc[ni] = (f32x4){0.f, 0.f, 0.f, 0.f};
    #pragma unroll
    for (int ni = 0; ni < 4; ++ni) {
        const bf16x8 b0 = *reinterpret_cast<const bf16x8*>(&Bs[(ni * 16 + l15) * 72 + quad * 8]);
        const bf16x8 b1 = *reinterpret_cast<const bf16x8*>(&Bs[(ni * 16 + l15) * 72 + 32 + quad * 8]);
        yacc[ni] = __builtin_amdgcn_mfma_f32_16x16x32_bf16(af[0], b0, yacc[ni], 0, 0, 0);
        yacc[ni] = __builtin_amdgcn_mfma_f32_16x16x32_bf16(af[1], b1, yacc[ni], 0, 0, 0);
    }
    const int mrow = wave * 16 + quad * 4;   // C/D: row = quad*4+reg within 16x16
    {
        float es[4];
        #pragma unroll
        for (int reg = 0; reg < 4; ++reg) es[reg] = expf(acs_s[lt * 64 + mrow + reg]);
        #pragma unroll
        for (int ni = 0; ni < 4; ++ni)
            #pragma unroll
            for (int reg = 0; reg < 4; ++reg) yacc[ni][reg] *= es[reg];
    }

    for (int st = 0; st <= lt; ++st) {
        __syncthreads();   // everyone done reading Bs/Xt/Sp from previous stage
        // stage B s-tile and XdtT s-slice (pure vec copies)
        #pragma unroll
        for (int e = 0; e < 2; ++e) {
            const int u = e * 256 + tid;
            const int r = u >> 3, seg = (u & 7) * 8;
            *reinterpret_cast<bf16x8*>(&Bs[r * 72 + seg]) =
                *reinterpret_cast<const bf16x8*>(Bb16 + (rowbase + st * 64 + r) * 64 + seg);
            *reinterpret_cast<bf16x8*>(&Xt[r * 72 + seg]) =
                *reinterpret_cast<const bf16x8*>(xdsrc + r * 256 + st * 64 + seg);
        }
        __syncthreads();
        // S = C_lt(slice) @ B_st^T
        f32x4 sacc[4];
        #pragma unroll
        for (int ni = 0; ni < 4; ++ni) sacc[ni] = (f32x4){0.f, 0.f, 0.f, 0.f};
        #pragma unroll
        for (int ni = 0; ni < 4; ++ni) {
            const bf16x8 b0 = *reinterpret_cast<const bf16x8*>(&Bs[(ni * 16 + l15) * 72 + quad * 8]);
            const bf16x8 b1 = *reinterpret_cast<const bf16x8*>(&Bs[(ni * 16 + l15) * 72 + 32 + quad * 8]);
            sacc[ni] = __builtin_amdgcn_mfma_f32_16x16x32_bf16(af[0], b0, sacc[ni], 0, 0, 0);
            sacc[ni] = __builtin_amdgcn_mfma_f32_16x16x32_bf16(af[1], b1, sacc[ni], 0, 0, 0);
        }
        // decay + causal mask -> S' bf16
        #pragma unroll
        for (int reg = 0; reg < 4; ++reg) {
            const int l = lt * 64 + mrow + reg;
            const float al = acs_s[l];
            #pragma unroll
            for (int ni = 0; ni < 4; ++ni) {
                const int scol = ni * 16 + l15;
                const int sg = st * 64 + scol;
                float v = sacc[ni][reg] * expf(al - acs_s[sg]);
                if (st == lt && sg > l) v = 0.f;
                Sp[(mrow + reg) * 72 + scol] = (__bf16)v;
            }
        }
        __syncthreads();   // FENCE: S' writes visible (and compiler-ordered) before reads
        // Y += S' @ XdtT
        const bf16x8 as0 = *reinterpret_cast<const bf16x8*>(&Sp[(wave * 16 + l15) * 72 + quad * 8]);
        const bf16x8 as1 = *reinterpret_cast<const bf16x8*>(&Sp[(wave * 16 + l15) * 72 + 32 + quad * 8]);
        #pragma unroll
        for (int ni = 0; ni < 4; ++ni) {
            const bf16x8 x0 = *reinterpret_cast<const bf16x8*>(&Xt[(ni * 16 + l15) * 72 + quad * 8]);
            const bf16x8 x1 = *reinterpret_cast<const bf16x8*>(&Xt[(ni * 16 + l15) * 72 + 32 + quad * 8]);
            yacc[ni] = __builtin_amdgcn_mfma_f32_16x16x32_bf16(as0, x0, yacc[ni], 0, 0, 0);
            yacc[ni] = __builtin_amdgcn_mfma_f32_16x16x32_bf16(as1, x1, yacc[ni], 0, 0, 0);
        }
    }

    // epilogue: += D*x (fp32 x input), store bf16 Y
    const float Dh = Dvec[hi];
    #pragma unroll
    for (int reg = 0; reg < 4; ++reg) {
        const size_t tg = rowbase + lt * 64 + mrow + reg;
        #pragma unroll
        for (int ni = 0; ni < 4; ++ni) {
            const int p = ni * 16 + l15;
            const float v = yacc[ni][reg] + Dh * x[tg * kDModel + hi * kP + p];
            Y[tg * kDModel + hi * kP + p] = (bf16_t)v;
        }
    }
}

extern "C" void kernel_launch(void* const* d_in, const int* in_sizes, int n_in,
                              void* d_out, int out_size, void* d_ws, size_t ws_size,
                              hipStream_t stream)
{
    (void)in_sizes; (void)n_in; (void)out_size; (void)ws_size;
    const float* x     = (const float*)d_in[0];
    const float* A_log = (const float*)d_in[1];
    const float* Dvec  = (const float*)d_in[2];
    const float* B_w   = (const float*)d_in[3];
    const float* B_b   = (const float*)d_in[4];
    const float* C_w   = (const float*)d_in[5];
    const float* C_b   = (const float*)d_in[6];
    const float* dt_w  = (const float*)d_in[7];
    const float* dt_b  = (const float*)d_in[8];
    const float* out_w = (const float*)d_in[9];
    const float* out_b = (const float*)d_in[10];
    float* out = (float*)d_out;

    // workspace layout
    float* ws = (float*)d_ws;
    float* dtm    = ws;                                                  // 2*4096*32
    float* Acs    = dtm + (size_t)kM * kHeads;                           // 2*32*16*256
    float* states = Acs + (size_t)kBatch * kHeads * kNChunk * kChunk;    // 2*16*32*64*64
    float* prevs  = states + (size_t)kBatch * kNChunk * kHeads * kP * kState;
    bf16_t* xb    = (bf16_t*)(prevs + (size_t)kBatch * kNChunk * kHeads * kP * kState);
    bf16_t* Y     = xb;                               // ALIAS: xb dead after xdtT_kernel
    bf16_t* Bb16  = xb + (size_t)kM * kDModel;        // [t][64]
    bf16_t* Cb16  = Bb16 + (size_t)kM * kState;       // [t][64]
    bf16_t* xdtT  = Cb16 + (size_t)kM * kState;       // [(b,c,h)][64][256]
    bf16_t* bTg   = xdtT + (size_t)kM * kDModel;      // [(b,c)][64][256]
    bf16_t* wcat  = bTg + (size_t)kBatch * kNChunk * kState * kChunk;
    bf16_t* wob   = wcat + (size_t)256 * kDModel;     // bf16 out_w [2048,2048]

    const dim3 blk(256);
    // dtype converts
    cvt_bf16_kernel<<<dim3(kM * kDModel / 1024), blk, 0, stream>>>(x, xb, kM * kDModel);
    cvt_bf16_kernel<<<dim3(kDModel * kDModel / 1024), blk, 0, stream>>>(out_w, wob, kDModel * kDModel);
    pack_w_kernel<<<dim3(256 * kDModel / 256), blk, 0, stream>>>(B_w, C_w, dt_w, wcat);
    // fused B/C/dt projection (MFMA) -> bf16 B, bf16 C, fp32 softplus dt
    gemm_mfma<1><<<dim3(2, kM / 128), blk, 0, stream>>>(xb, wcat, kDModel, 0,
                                                        B_b, C_b, dt_b,
                                                        nullptr, Bb16, Cb16, dtm);
    // per-chunk cumulative decay
    dtcumsum_kernel<<<dim3(kBatch * kHeads * kNChunk), dim3(kChunk), 0, stream>>>(dtm, A_log, Acs);
    // B chunk transpose (shared across heads)
    bT_kernel<<<dim3(kBatch * kNChunk), blk, 0, stream>>>(Bb16, bTg);
    // xdt transposed per (b,c,h)  [last reader of xb]
    xdtT_kernel<<<dim3(kBatch * kNChunk * kHeads), blk, 0, stream>>>(xb, dtm, xdtT);
    // per-chunk end states (MFMA)
    states_mfma<<<dim3(kBatch * kNChunk * kHeads), blk, 0, stream>>>(xdtT, bTg, Acs, states);
    // inter-chunk recurrence (16 steps)
    chunkscan_kernel<<<dim3(kBatch * kHeads), blk, 0, stream>>>(states, Acs, prevs);
    // intra-chunk Y (MFMA)  [writes Y == xb alias]
    ychunk_mfma<<<dim3(kBatch * kNChunk * kHeads * 4), blk, 0, stream>>>(
        x, Bb16, Cb16, xdtT, Acs, prevs, Dvec, Y);
    // out-projection (MFMA)
    gemm_mfma<0><<<dim3(kDModel / 128, kM / 128), blk, 0, stream>>>(Y, wob, kDModel, kDModel,
                                                                    out_b, nullptr, nullptr,
                                                                    out, nullptr, nullptr, nullptr);
}